// Round 10
// baseline (367.208 us; speedup 1.0000x reference)
//
#include <hip/hip_runtime.h>

#define N_ 65536
#define D_ 768
#define L_ 100
#define B_ 8192

// ---- prep grid layout -------------------------------------------------------
#define AT_BLK 1200   // Att2 tiles: 25 q-tiles x 192 d-tiles, 4 waves/block
#define W2T_BLK 1200  // W2 tiles: 192 d-tiles x 25 l-tiles, 4 waves/block
#define CQB 25        // cq: wave per q
#define B2B 7         // b2: 25 l-tile waves
#define OFFB 32       // 8192 binary searches
#define PREP_BLK (AT_BLK + W2T_BLK + CQB + B2B + OFFB)  // 2464

__device__ __forceinline__ int lower_bound_seg(const int* __restrict__ seg, int key) {
    int lo = 0, hi = N_;
    while (lo < hi) {
        int mid = (lo + hi) >> 1;
        if (seg[mid] < key) lo = mid + 1; else hi = mid;
    }
    return lo;
}

// ---- kernel 0: WclsT = Wcls^T ----------------------------------------------
__global__ __launch_bounds__(256) void tr_kernel(
    const float* __restrict__ Wcls, float* __restrict__ WclsT)
{
    int j  = blockIdx.x * 4 + (threadIdx.x >> 6);   // 192 blocks x 4 rows
    int l0 = threadIdx.x & 63;
    float v0 = Wcls[(size_t)j * L_ + l0];           // coalesced read
    WclsT[(size_t)l0 * D_ + j] = v0;                // scattered write (fire+forget)
    if (l0 < L_ - 64) {
        float v1 = Wcls[(size_t)j * L_ + 64 + l0];
        WclsT[(size_t)(64 + l0) * D_ + j] = v1;
    }
}

__device__ __forceinline__ float dot4(float4 a, float4 b) {
    return a.x * b.x + a.y * b.y + a.z * b.z + a.w * b.w;
}

// Att2 = att @ Wfc^T ; W2 = Wfc @ Wcls (via WclsT) ; cq ; b2 ; off[]
__global__ __launch_bounds__(256) void prep_kernel(
    const float* __restrict__ Wfc,  const float* __restrict__ att,
    const float* __restrict__ WclsT, const float* __restrict__ bfc,
    const int*   __restrict__ seg,
    float* __restrict__ Att2, float* __restrict__ W2,
    float* __restrict__ cq,   float* __restrict__ b2,
    int*   __restrict__ off)
{
    int bid  = blockIdx.x;
    int wv   = threadIdx.x >> 6;
    int lane = threadIdx.x & 63;

    if (bid < AT_BLK) {
        // Att2[q0..+3][d0..+3] = att rows x Wfc rows
        int t  = bid * 4 + wv;
        int q0 = (t / 192) * 4;
        int d0 = (t % 192) * 4;
        const float4* at4 = (const float4*)att;
        const float4* wf4 = (const float4*)Wfc;
        float acc[4][4];
#pragma unroll
        for (int qi = 0; qi < 4; ++qi)
#pragma unroll
            for (int di = 0; di < 4; ++di) acc[qi][di] = 0.f;
#pragma unroll
        for (int jj = 0; jj < 3; ++jj) {
            float4 av[4], wv4[4];
#pragma unroll
            for (int r = 0; r < 4; ++r) av[r]  = at4[(size_t)(q0 + r) * 192 + lane + jj * 64];
#pragma unroll
            for (int r = 0; r < 4; ++r) wv4[r] = wf4[(size_t)(d0 + r) * 192 + lane + jj * 64];
#pragma unroll
            for (int qi = 0; qi < 4; ++qi)
#pragma unroll
                for (int di = 0; di < 4; ++di)
                    acc[qi][di] += dot4(av[qi], wv4[di]);
        }
#pragma unroll
        for (int qi = 0; qi < 4; ++qi)
#pragma unroll
            for (int di = 0; di < 4; ++di) {
                float s = acc[qi][di];
#pragma unroll
                for (int o = 32; o > 0; o >>= 1) s += __shfl_xor(s, o, 64);
                acc[qi][di] = s;
            }
        if (lane == 0) {
#pragma unroll
            for (int qi = 0; qi < 4; ++qi)
                *(float4*)(Att2 + (size_t)(q0 + qi) * D_ + d0) =
                    make_float4(acc[qi][0], acc[qi][1], acc[qi][2], acc[qi][3]);
        }
    } else if (bid < AT_BLK + W2T_BLK) {
        // W2[d0..+3][l0..+3] = Wfc rows x WclsT rows  (identical tile pattern)
        int t  = (bid - AT_BLK) * 4 + wv;
        int d0 = (t / 25) * 4;
        int l0 = (t % 25) * 4;
        const float4* wf4 = (const float4*)Wfc;
        const float4* wc4 = (const float4*)WclsT;
        float acc[4][4];
#pragma unroll
        for (int di = 0; di < 4; ++di)
#pragma unroll
            for (int li = 0; li < 4; ++li) acc[di][li] = 0.f;
#pragma unroll
        for (int jj = 0; jj < 3; ++jj) {
            float4 dv[4], lv[4];
#pragma unroll
            for (int r = 0; r < 4; ++r) dv[r] = wf4[(size_t)(d0 + r) * 192 + lane + jj * 64];
#pragma unroll
            for (int r = 0; r < 4; ++r) lv[r] = wc4[(size_t)(l0 + r) * 192 + lane + jj * 64];
#pragma unroll
            for (int di = 0; di < 4; ++di)
#pragma unroll
                for (int li = 0; li < 4; ++li)
                    acc[di][li] += dot4(dv[di], lv[li]);
        }
#pragma unroll
        for (int di = 0; di < 4; ++di)
#pragma unroll
            for (int li = 0; li < 4; ++li) {
                float s = acc[di][li];
#pragma unroll
                for (int o = 32; o > 0; o >>= 1) s += __shfl_xor(s, o, 64);
                acc[di][li] = s;
            }
        if (lane == 0) {
#pragma unroll
            for (int di = 0; di < 4; ++di)
                *(float4*)(W2 + (size_t)(d0 + di) * L_ + l0) =
                    make_float4(acc[di][0], acc[di][1], acc[di][2], acc[di][3]);
        }
    } else if (bid < AT_BLK + W2T_BLK + CQB) {
        // cq[q] = att[q] . bfc
        int q = (bid - (AT_BLK + W2T_BLK)) * 4 + wv;
        const float4* ar = (const float4*)(att + (size_t)q * D_);
        const float4* br = (const float4*)bfc;
        float s = 0.f;
#pragma unroll
        for (int jj = 0; jj < 3; ++jj)
            s += dot4(ar[lane + jj * 64], br[lane + jj * 64]);
#pragma unroll
        for (int o = 32; o > 0; o >>= 1) s += __shfl_xor(s, o, 64);
        if (lane == 0) cq[q] = s;
    } else if (bid < AT_BLK + W2T_BLK + CQB + B2B) {
        // b2[l0..+3] = bfc . WclsT rows
        int t = (bid - (AT_BLK + W2T_BLK + CQB)) * 4 + wv;
        if (t < 25) {
            int l0 = t * 4;
            const float4* wc4 = (const float4*)WclsT;
            const float4* bf4 = (const float4*)bfc;
            float acc[4] = {0.f, 0.f, 0.f, 0.f};
#pragma unroll
            for (int jj = 0; jj < 3; ++jj) {
                float4 bv = bf4[lane + jj * 64];
#pragma unroll
                for (int r = 0; r < 4; ++r)
                    acc[r] += dot4(bv, wc4[(size_t)(l0 + r) * 192 + lane + jj * 64]);
            }
#pragma unroll
            for (int r = 0; r < 4; ++r) {
                float s = acc[r];
#pragma unroll
                for (int o = 32; o > 0; o >>= 1) s += __shfl_xor(s, o, 64);
                acc[r] = s;
            }
            if (lane == 0)
                *(float4*)(b2 + l0) = make_float4(acc[0], acc[1], acc[2], acc[3]);
        }
    } else {
        // off[b] table
        int b = (bid - (AT_BLK + W2T_BLK + CQB + B2B)) * 256 + threadIdx.x;
        off[b] = lower_bound_seg(seg, b);
        if (b == 0) off[B_] = N_;
    }
}

// ---- bag v7: one wave per bag, explicit 2-stage software pipeline -----------
// Pair k+1's H/Att2/cq loads are ISSUED before pair k's reduce/exp/accumulate
// runs (~150cy of VALU hides the load latency); pair k+1's partial dots then
// consume the Att2 regs immediately. Invalid rows: cq=-inf -> w=0, branch-free.
// __launch_bounds__(256,4) pins VGPR <= 128 (4 waves/SIMD).
__global__ __launch_bounds__(256, 4) void bag_kernel(
    const float* __restrict__ H, const float* __restrict__ Att2,
    const float* __restrict__ cq, const int* __restrict__ query,
    const int* __restrict__ off,
    float* __restrict__ hbar, float* __restrict__ sflag)
{
    int wv   = threadIdx.x >> 6;
    int lane = threadIdx.x & 63;
    int b    = blockIdx.x * 4 + wv;
    int s    = off[b], e = off[b + 1];

    float z = 0.f;
    float acc[12];
#pragma unroll
    for (int j = 0; j < 12; ++j) acc[j] = 0.f;

    if (e > s) {
        float4 hC[2][3];                 // current pair's H slices
        float  pC[2], cqC[2];            // current pair's partial dots + cq

        // ---- prologue: load pair 0 and compute its partial dots ----
#pragma unroll
        for (int u = 0; u < 2; ++u) {
            int i = s + u;
            if (i < e) {
                const float4* hr = (const float4*)(H    + (size_t)i * D_);
                const float4* ar = (const float4*)(Att2 + (size_t)query[i] * D_);
                float p = 0.f;
#pragma unroll
                for (int jj = 0; jj < 3; ++jj) {
                    hC[u][jj] = hr[lane + jj * 64];
                    p += dot4(hC[u][jj], ar[lane + jj * 64]);
                }
                pC[u]  = p;
                cqC[u] = cq[query[i]];
            } else {
                pC[u] = 0.f; cqC[u] = -INFINITY;
#pragma unroll
                for (int jj = 0; jj < 3; ++jj) hC[u][jj] = make_float4(0.f,0.f,0.f,0.f);
            }
        }

        for (int base = s; base < e; base += 2) {
            // ---- stage 1: issue next pair's loads (in flight during stage 2) ----
            float4 hN[2][3], aN[2][3];
            float  cqN[2];
#pragma unroll
            for (int u = 0; u < 2; ++u) {
                int i = base + 2 + u;
                if (i < e) {
                    const float4* hr = (const float4*)(H    + (size_t)i * D_);
                    const float4* ar = (const float4*)(Att2 + (size_t)query[i] * D_);
#pragma unroll
                    for (int jj = 0; jj < 3; ++jj) {
                        hN[u][jj] = hr[lane + jj * 64];
                        aN[u][jj] = ar[lane + jj * 64];
                    }
                    cqN[u] = cq[query[i]];
                } else {
                    cqN[u] = -INFINITY;
#pragma unroll
                    for (int jj = 0; jj < 3; ++jj) {
                        hN[u][jj] = make_float4(0.f,0.f,0.f,0.f);
                        aN[u][jj] = make_float4(0.f,0.f,0.f,0.f);
                    }
                }
            }

            // ---- stage 2: finish current pair (VALU; hides the loads) ----
            float p0 = pC[0], p1 = pC[1];
#pragma unroll
            for (int o = 32; o > 0; o >>= 1) {
                p0 += __shfl_xor(p0, o, 64);
                p1 += __shfl_xor(p1, o, 64);
            }
            float w0 = __expf(p0 + cqC[0]);      // -inf -> 0
            float w1 = __expf(p1 + cqC[1]);
            z += w0 + w1;
#pragma unroll
            for (int jj = 0; jj < 3; ++jj) {
                acc[jj*4+0] += w0 * hC[0][jj].x + w1 * hC[1][jj].x;
                acc[jj*4+1] += w0 * hC[0][jj].y + w1 * hC[1][jj].y;
                acc[jj*4+2] += w0 * hC[0][jj].z + w1 * hC[1][jj].z;
                acc[jj*4+3] += w0 * hC[0][jj].w + w1 * hC[1][jj].w;
            }

            // ---- stage 3: next pair's partial dots (aN dies here); rotate ----
#pragma unroll
            for (int u = 0; u < 2; ++u) {
                float p = 0.f;
#pragma unroll
                for (int jj = 0; jj < 3; ++jj) {
                    p += dot4(hN[u][jj], aN[u][jj]);
                    hC[u][jj] = hN[u][jj];
                }
                pC[u]  = p;
                cqC[u] = cqN[u];
            }
        }
    }

    float invz = (e > s) ? 1.f / z : 0.f;
    float4* o4 = (float4*)(hbar + (size_t)b * D_);
#pragma unroll
    for (int jj = 0; jj < 3; ++jj)
        o4[lane + jj * 64] = make_float4(acc[jj*4+0] * invz, acc[jj*4+1] * invz,
                                         acc[jj*4+2] * invz, acc[jj*4+3] * invz);
    if (lane == 0) sflag[b] = (e > s) ? 1.f : 0.f;
}

// ---- cls v5 (R5/R8-proven, verbatim): out = hbar @ W2 + sflag*b2 + b_cls ----
__global__ __launch_bounds__(256) void cls_kernel(
    const float* __restrict__ hbar, const float* __restrict__ W2,
    const float* __restrict__ b2,   const float* __restrict__ bcls,
    const float* __restrict__ sflag, float* __restrict__ out)
{
    __shared__ float sm[8 * D_];                 // 24 KB
    int b0  = blockIdx.x * 8;
    int tid = threadIdx.x;
    const float4* src = (const float4*)(hbar + (size_t)b0 * D_);
    float4* dst = (float4*)sm;
#pragma unroll
    for (int j = 0; j < 6; ++j) dst[tid + j * 256] = src[tid + j * 256];
    __syncthreads();

    int g = tid >> 7;                            // bag half: 0 -> bags 0..3, 1 -> 4..7
    int l = tid & 127;
    if (l < L_) {
        float a0 = 0.f, a1 = 0.f, a2 = 0.f, a3 = 0.f;
        const float* smg = sm + g * 4 * D_;
        for (int d0 = 0; d0 < D_; d0 += 4) {
            float w0 = W2[(size_t)(d0 + 0) * L_ + l];
            float w1 = W2[(size_t)(d0 + 1) * L_ + l];
            float w2 = W2[(size_t)(d0 + 2) * L_ + l];
            float w3 = W2[(size_t)(d0 + 3) * L_ + l];
            float4 s0 = *(const float4*)(smg + 0 * D_ + d0);
            float4 s1 = *(const float4*)(smg + 1 * D_ + d0);
            float4 s2 = *(const float4*)(smg + 2 * D_ + d0);
            float4 s3 = *(const float4*)(smg + 3 * D_ + d0);
            a0 += s0.x * w0 + s0.y * w1 + s0.z * w2 + s0.w * w3;
            a1 += s1.x * w0 + s1.y * w1 + s1.z * w2 + s1.w * w3;
            a2 += s2.x * w0 + s2.y * w1 + s2.z * w2 + s2.w * w3;
            a3 += s3.x * w0 + s3.y * w1 + s3.z * w2 + s3.w * w3;
        }
        float bb = bcls[l], b2v = b2[l];
        int b = b0 + g * 4;
        out[(size_t)(b + 0) * L_ + l] = a0 + sflag[b + 0] * b2v + bb;
        out[(size_t)(b + 1) * L_ + l] = a1 + sflag[b + 1] * b2v + bb;
        out[(size_t)(b + 2) * L_ + l] = a2 + sflag[b + 2] * b2v + bb;
        out[(size_t)(b + 3) * L_ + l] = a3 + sflag[b + 3] * b2v + bb;
    }
}

extern "C" void kernel_launch(void* const* d_in, const int* in_sizes, int n_in,
                              void* d_out, int out_size, void* d_ws, size_t ws_size,
                              hipStream_t stream) {
    const float* h    = (const float*)d_in[0];
    const float* Wfc  = (const float*)d_in[1];
    const float* bfc  = (const float*)d_in[2];
    const float* att  = (const float*)d_in[3];
    const float* Wcls = (const float*)d_in[4];
    const float* bcls = (const float*)d_in[5];
    const int*   query= (const int*)d_in[6];
    const int*   seg  = (const int*)d_in[7];
    float* out = (float*)d_out;

    char* w = (char*)d_ws;
    float* Att2  = (float*)w;  w += (size_t)L_ * D_ * 4;
    float* W2    = (float*)w;  w += (size_t)D_ * L_ * 4;
    float* WclsT = (float*)w;  w += (size_t)L_ * D_ * 4;
    float* cq    = (float*)w;  w += 128 * 4;
    float* b2    = (float*)w;  w += 128 * 4;
    float* sflag = (float*)w;  w += (size_t)B_ * 4;
    int*   off   = (int*)w;    w += (size_t)(B_ + 128) * 4;
    float* hbar  = (float*)w;  // B_*D_*4 = 25 MB

    tr_kernel  <<<D_ / 4, 256, 0, stream>>>(Wcls, WclsT);
    prep_kernel<<<PREP_BLK, 256, 0, stream>>>(
        Wfc, att, WclsT, bfc, seg, Att2, W2, cq, b2, off);
    bag_kernel <<<B_ / 4, 256, 0, stream>>>(h, Att2, cq, query, off, hbar, sflag);
    cls_kernel <<<B_ / 8, 256, 0, stream>>>(hbar, W2, b2, bcls, sflag, out);
}